// Round 1
// baseline (198.921 us; speedup 1.0000x reference)
//
#include <hip/hip_runtime.h>

// DSQG attention, J=12 causal offsets, f32.
// Layout: one 16-lane group per position; lane holds 4 channels (float4).
// All global accesses are 1KB/wave coalesced. No LDS; rely on L2 via XCD swizzle.

namespace {

constexpr int J   = 12;
constexpr int B_  = 2;
constexpr int H_  = 16;
constexpr int N_  = 4096;
constexpr int HD_ = 64;
constexpr int OFFS[J] = {1, 2, 4, 8, 16, 64, 96, 192, 384, 512, 768, 1024};

__global__ __launch_bounds__(256) void dsqg_kernel(
    const float* __restrict__ q, const float* __restrict__ k,
    const float* __restrict__ v, const float* __restrict__ pb,
    const float* __restrict__ se, const float* __restrict__ phase_base,
    const float* __restrict__ phase_gain, const float* __restrict__ y_pre,
    const float* __restrict__ z_pre, float* __restrict__ out)
{
    // XCD-locality swizzle: give each XCD a contiguous range of work so the
    // 12-fold k/v row re-reads (reuse window 1024 rows = 512 KB) hit its L2.
    const int raw = blockIdx.x;
    const int per = gridDim.x >> 3;
    const int wid = (raw & 7) * per + (raw >> 3);

    const int bh    = wid >> 8;       // 256 blocks (of 16 positions) per (b,h)
    const int chunk = wid & 255;
    const int h     = bh & (H_ - 1);

    const int lane = threadIdx.x & 63;
    const int wave = threadIdx.x >> 6;
    const int grp  = lane & 15;                        // lane within position group
    const int n    = chunk * 16 + wave * 4 + (lane >> 4);

    const size_t base4 = (size_t)bh * N_ * (HD_ / 4);  // float4 units
    const float4* q4 = (const float4*)q + base4;
    const float4* k4 = (const float4*)k + base4;
    const float4* v4 = (const float4*)v + base4;
    float4*       o4 = (float4*)out + base4;

    const float4 qr = q4[(size_t)n * 16 + grp];

    float4 seg[J];
    float  pbh[J];
#pragma unroll
    for (int i = 0; i < J; ++i) {
        seg[i] = ((const float4*)se)[i * 16 + grp];
        pbh[i] = pb[i * H_ + h];
    }

    const float sc = 0.125f;  // 1/sqrt(64)

    // ---- pass 1: 12 scores -------------------------------------------------
    float s[J];
#pragma unroll
    for (int i = 0; i < J; ++i) {
        const int d = OFFS[i];
        const int m = (n >= d) ? (n - d) : 0;          // clamp; invalid masked below
        const float4 kr = k4[(size_t)m * 16 + grp];
        float p = qr.x * (kr.x + seg[i].x)
                + qr.y * (kr.y + seg[i].y)
                + qr.z * (kr.z + seg[i].z)
                + qr.w * (kr.w + seg[i].w);
        // reduce across the 16-lane position group (masks < 16 never cross it)
        p += __shfl_xor(p, 1);
        p += __shfl_xor(p, 2);
        p += __shfl_xor(p, 4);
        p += __shfl_xor(p, 8);
        s[i] = (n >= d) ? (p * sc + pbh[i]) : -INFINITY;
    }

    float mx = s[0];
#pragma unroll
    for (int i = 1; i < J; ++i) mx = fmaxf(mx, s[i]);

    const float2 yp = ((const float2*)y_pre)[(size_t)bh * N_ + n];

    // ---- pass 2: softmax weights + weighted (rotated) value sum ------------
    float4 acc = make_float4(0.f, 0.f, 0.f, 0.f);
    float  sum = 0.f;
#pragma unroll
    for (int i = 0; i < J; ++i) {
        const int d = OFFS[i];
        const int m = (n >= d) ? (n - d) : 0;
        const float e = __expf(s[i] - mx);             // -inf -> 0 (n==0 fixed at store)
        sum += e;
        float4 vr = v4[(size_t)m * 16 + grp];
        if (i >= 4 && grp == 0) {                      // channels 0..3 live on grp==0
            const int pi = i - 4;
            const float2 zp = ((const float2*)z_pre)[(size_t)bh * N_ + m];
            const float b0 = phase_base[(pi * H_ + h) * 2 + 0];
            const float b1 = phase_base[(pi * H_ + h) * 2 + 1];
            const float g0 = phase_gain[(pi * H_ + h) * 2 + 0];
            const float g1 = phase_gain[(pi * H_ + h) * 2 + 1];
            const float th0 = b0 + g0 * yp.x * zp.x;
            const float th1 = b1 + g1 * yp.y * zp.y;
            float s0, c0, s1, c1;
            __sincosf(th0, &s0, &c0);
            __sincosf(th1, &s1, &c1);
            const float v0 = vr.x, v1 = vr.y, v2 = vr.z, v3 = vr.w;
            vr.x = c0 * v0 - s0 * v1;
            vr.y = s0 * v0 + c0 * v1;
            vr.z = c1 * v2 - s1 * v3;
            vr.w = s1 * v2 + c1 * v3;
        }
        acc.x += e * vr.x;
        acc.y += e * vr.y;
        acc.z += e * vr.z;
        acc.w += e * vr.w;
    }

    float4 res;
    if (n >= 1) {                    // at least offset d=1 valid -> sum >= 1
        const float inv = 1.0f / sum;
        res = make_float4(acc.x * inv, acc.y * inv, acc.z * inv, acc.w * inv);
    } else {                         // n==0: no valid offset -> zeros
        res = make_float4(0.f, 0.f, 0.f, 0.f);
    }
    o4[(size_t)n * 16 + grp] = res;
}

} // namespace

extern "C" void kernel_launch(void* const* d_in, const int* in_sizes, int n_in,
                              void* d_out, int out_size, void* d_ws, size_t ws_size,
                              hipStream_t stream) {
    const float* q          = (const float*)d_in[0];
    const float* k          = (const float*)d_in[1];
    const float* v          = (const float*)d_in[2];
    const float* pb         = (const float*)d_in[3];
    const float* se         = (const float*)d_in[4];
    const float* phase_base = (const float*)d_in[5];
    const float* phase_gain = (const float*)d_in[6];
    const float* y_pre      = (const float*)d_in[7];
    const float* z_pre      = (const float*)d_in[8];
    float* out              = (float*)d_out;

    const int positions = B_ * H_ * N_;          // 131072
    const int blocks    = positions / 16;        // 16 positions per 256-thread block
    dsqg_kernel<<<blocks, 256, 0, stream>>>(q, k, v, pb, se, phase_base,
                                            phase_gain, y_pre, z_pre, out);
}

// Round 2
// 190.054 us; speedup vs baseline: 1.0467x; 1.0467x over previous
//
#include <hip/hip_runtime.h>

// DSQG attention, J=12 causal offsets, f32.
// One 16-lane group per position; lane holds 4 channels (float4).
// R2: explicit prefetch arrays (12 k rows, then 12 v rows) for MLP;
// max-free softmax (scores are O(+-6)); early z prefetch; native sin/cos.

namespace {

constexpr int J   = 12;
constexpr int B_  = 2;
constexpr int H_  = 16;
constexpr int N_  = 4096;
constexpr int HD_ = 64;
constexpr int OFFS[J] = {1, 2, 4, 8, 16, 64, 96, 192, 384, 512, 768, 1024};

__global__ __launch_bounds__(256) void dsqg_kernel(
    const float* __restrict__ q, const float* __restrict__ k,
    const float* __restrict__ v, const float* __restrict__ pb,
    const float* __restrict__ se, const float* __restrict__ phase_base,
    const float* __restrict__ phase_gain, const float* __restrict__ y_pre,
    const float* __restrict__ z_pre, float* __restrict__ out)
{
    // XCD-locality swizzle: contiguous work range per XCD so k/v row re-reads
    // (reuse window <= 1024 rows = 512 KB) stay in that XCD's 4 MB L2.
    const int raw = blockIdx.x;
    const int per = gridDim.x >> 3;
    const int wid = (raw & 7) * per + (raw >> 3);

    const int bh    = wid >> 8;       // 256 blocks (16 positions each) per (b,h)
    const int chunk = wid & 255;
    const int h     = bh & (H_ - 1);

    const int lane = threadIdx.x & 63;
    const int wave = threadIdx.x >> 6;
    const int grp  = lane & 15;                        // lane within position group
    const int n    = chunk * 16 + wave * 4 + (lane >> 4);

    const size_t base4 = (size_t)bh * N_ * (HD_ / 4);  // float4 units
    const float4* q4 = (const float4*)q + base4;
    const float4* k4 = (const float4*)k + base4;
    const float4* v4 = (const float4*)v + base4;
    float4*       o4 = (float4*)out + base4;

    const float4 qr = q4[(size_t)n * 16 + grp];

    // row indices (clamped; invalid offsets masked to weight 0 later)
    int m[J];
    bool ok[J];
#pragma unroll
    for (int i = 0; i < J; ++i) {
        ok[i] = (n >= OFFS[i]);
        m[i]  = ok[i] ? (n - OFFS[i]) : 0;
    }

    // prefetch key-side phase features for the 8 rotated offsets (grp==0 only)
    float2 zr[8];
    float2 yp = make_float2(0.f, 0.f);
    if (grp == 0) {
        yp = ((const float2*)y_pre)[(size_t)bh * N_ + n];
#pragma unroll
        for (int pi = 0; pi < 8; ++pi)
            zr[pi] = ((const float2*)z_pre)[(size_t)bh * N_ + m[pi + 4]];
    }

    // ---- issue all 12 k-row loads back-to-back ------------------------------
    float4 kr[J];
#pragma unroll
    for (int i = 0; i < J; ++i) kr[i] = k4[(size_t)m[i] * 16 + grp];

    // partial dots: p_i = q . (k_i + se_i)  (per-lane 4-channel partial)
    float p[J];
#pragma unroll
    for (int i = 0; i < J; ++i) {
        const float4 seg = ((const float4*)se)[i * 16 + grp];
        float t = qr.x * seg.x + qr.y * seg.y + qr.z * seg.z + qr.w * seg.w;
        t = fmaf(qr.x, kr[i].x, t);
        t = fmaf(qr.y, kr[i].y, t);
        t = fmaf(qr.z, kr[i].z, t);
        p[i] = fmaf(qr.w, kr[i].w, t);
    }

    // ---- issue all 12 v-row loads now; latency hides under the butterfly ----
    float4 vr[J];
#pragma unroll
    for (int i = 0; i < J; ++i) vr[i] = v4[(size_t)m[i] * 16 + grp];

    // butterfly reduction over the 16-lane group, 12 independent chains
#pragma unroll
    for (int stage = 1; stage <= 8; stage <<= 1) {
#pragma unroll
        for (int i = 0; i < J; ++i) p[i] += __shfl_xor(p[i], stage);
    }

    const float sc = 0.125f;  // 1/sqrt(64)
    float e[J];
    float sum = 0.f;
#pragma unroll
    for (int i = 0; i < J; ++i) {
        const float si = fmaf(p[i], sc, pb[i * H_ + h]);
        e[i] = ok[i] ? __expf(si) : 0.f;   // max-free: |si| ~ O(6), f32-safe
        sum += e[i];
    }

    // ---- phase rotation of channels 0..3 (grp==0 lanes only) ----------------
    if (grp == 0) {
#pragma unroll
        for (int pi = 0; pi < 8; ++pi) {
            const int i = pi + 4;
            const float b0 = phase_base[(pi * H_ + h) * 2 + 0];
            const float b1 = phase_base[(pi * H_ + h) * 2 + 1];
            const float g0 = phase_gain[(pi * H_ + h) * 2 + 0];
            const float g1 = phase_gain[(pi * H_ + h) * 2 + 1];
            const float th0 = fmaf(g0, yp.x * zr[pi].x, b0);
            const float th1 = fmaf(g1, yp.y * zr[pi].y, b1);
            const float c0 = __cosf(th0), s0 = __sinf(th0);
            const float c1 = __cosf(th1), s1 = __sinf(th1);
            const float v0 = vr[i].x, v1 = vr[i].y, v2 = vr[i].z, v3 = vr[i].w;
            vr[i].x = c0 * v0 - s0 * v1;
            vr[i].y = s0 * v0 + c0 * v1;
            vr[i].z = c1 * v2 - s1 * v3;
            vr[i].w = s1 * v2 + c1 * v3;
        }
    }

    // ---- weighted sum --------------------------------------------------------
    float4 acc = make_float4(0.f, 0.f, 0.f, 0.f);
#pragma unroll
    for (int i = 0; i < J; ++i) {
        acc.x = fmaf(e[i], vr[i].x, acc.x);
        acc.y = fmaf(e[i], vr[i].y, acc.y);
        acc.z = fmaf(e[i], vr[i].z, acc.z);
        acc.w = fmaf(e[i], vr[i].w, acc.w);
    }

    float4 res;
    if (n >= 1) {                    // offset d=1 valid -> sum >= e[0] > 0
        const float inv = 1.0f / sum;
        res = make_float4(acc.x * inv, acc.y * inv, acc.z * inv, acc.w * inv);
    } else {                         // n==0: no valid offset -> zeros
        res = make_float4(0.f, 0.f, 0.f, 0.f);
    }
    o4[(size_t)n * 16 + grp] = res;
}

} // namespace

extern "C" void kernel_launch(void* const* d_in, const int* in_sizes, int n_in,
                              void* d_out, int out_size, void* d_ws, size_t ws_size,
                              hipStream_t stream) {
    const float* q          = (const float*)d_in[0];
    const float* k          = (const float*)d_in[1];
    const float* v          = (const float*)d_in[2];
    const float* pb         = (const float*)d_in[3];
    const float* se         = (const float*)d_in[4];
    const float* phase_base = (const float*)d_in[5];
    const float* phase_gain = (const float*)d_in[6];
    const float* y_pre      = (const float*)d_in[7];
    const float* z_pre      = (const float*)d_in[8];
    float* out              = (float*)d_out;

    const int positions = B_ * H_ * N_;          // 131072
    const int blocks    = positions / 16;        // 16 positions per 256-thread block
    dsqg_kernel<<<blocks, 256, 0, stream>>>(q, k, v, pb, se, phase_base,
                                            phase_gain, y_pre, z_pre, out);
}